// Round 12
// baseline (220.311 us; speedup 1.0000x reference)
//
#include <hip/hip_runtime.h>

typedef __bf16 bf16x8 __attribute__((ext_vector_type(8)));
typedef float  f32x4  __attribute__((ext_vector_type(4)));

#define HD     512            // H*D
#define NITEMS 4096           // 4 tt x 8 seg x 128 (b,h)
#define C1     8.6316745750310966e-05f  // ALPHA/1024
#define C2     0.12751793f              // ALPHA*log2(e)

static __device__ __forceinline__ unsigned int cvt_pk_bf16(float lo, float hi) {
    unsigned int r;
    asm("v_cvt_pk_bf16_f32 %0, %1, %2" : "=v"(r) : "v"(lo), "v"(hi));
    return r;
}

union PA8 { unsigned int u[4]; bf16x8 v; };

// Persistent 8-wave blocks, dynamic queue over UNIFORM small items:
// item = (tt, seg, G): 256-row tile t = T-1-tt, j-segment [seg*128,(seg+1)*128)
// clipped to the tile's causal jmax -> ~2000 valid items x ~2 chunk64s each
// (vs r7/r8's ~1 variable-size item per block: no balancing at all).
// Output is ACCUMULATED via unsafeAtomicAdd onto a zeroed d_out (HSTU is a
// plain sum over j), so j-segments of one tile can run on different blocks.
// Core compute = r8's verified machinery: 8 waves x 32 q-rows (2 subtiles
// share all LDS fragment reads), KV chunk 64, ping-pong LDS 2x32KB,
// reg-prefetch, lgkm-only barriers (global loads stay in flight).
__global__ __launch_bounds__(512)
void hstu_attn_fwd(const float* __restrict__ Q, const float* __restrict__ K,
                   const float* __restrict__ V,
                   const int* __restrict__ offs,
                   const int* __restrict__ ntgt,
                   float* __restrict__ Out,
                   unsigned int* __restrict__ ctr)
{
    __shared__ __align__(16) char smem[65536];
    __shared__ int s_item;

    const int tid = threadIdx.x;
    const int w = tid >> 6, lane = tid & 63, l15 = lane & 15, g8 = lane >> 4;

    // staging decode
    const int kj0 = tid >> 4, kd8 = tid & 15;   // K: rows kj0, kj0+32; 16B unit kd8
    const int vg0 = tid >> 7, vd  = tid & 127;  // V: groups vg0, vg0+4; column vd

    // bpermute addresses for the P exchange (bytes = lane*4)
    const int addrA = ((((g8 & 1) << 5) + l15) << 2);
    const int addrB = addrA + 64;

    for (;;) {
        __syncthreads();
        if (tid == 0) s_item = (int)atomicAdd(ctr, 1u);
        __syncthreads();
        const int it = s_item;
        if (it >= NITEMS) break;

        const int tt  = it >> 10;          // 0..3, top tiles first
        const int rem = it & 1023;
        const int seg = rem >> 7;          // 0..7, 128-j segment
        const int G   = rem & 127;
        const int b   = G >> 2, h = G & 3;

        const int s0 = offs[b];
        const int L  = offs[b + 1] - s0;
        const int T  = (L + 255) >> 8;     // 256-row tiles
        const int t  = T - 1 - tt;
        if (t < 0) continue;
        const int cap = L - ntgt[b];

        const int r0 = t << 8;
        const int jm = (r0 + 256 > cap) ? L : (r0 + 256);   // tile causal bound
        const int c_lo = seg << 1;
        int c_hi = (jm + 63) >> 6; if (c_hi > c_lo + 2) c_hi = c_lo + 2;
        if (c_lo >= c_hi) continue;        // segment beyond this tile's range

        const float* Kb = K + (size_t)s0 * HD + h * 128;
        const float* Vb = V + (size_t)s0 * HD + h * 128;

        const int wr0 = r0 + (w << 5);     // wave owns rows wr0..wr0+31

        int wave_jmax;
        if (wr0 >= L)            wave_jmax = 0;
        else if (wr0 + 32 > cap) wave_jmax = L;
        else                     wave_jmax = wr0 + 32;

        // ---- Q fragments (B-operand of swapped QK^T), two subtiles ----
        bf16x8 qa[2][4];
#pragma unroll
        for (int u = 0; u < 2; ++u) {
            int qr = wr0 + u * 16 + l15; if (qr > L - 1) qr = L - 1;
            const float* qp = Q + (size_t)(s0 + qr) * HD + h * 128 + g8 * 8;
#pragma unroll
            for (int kc = 0; kc < 4; ++kc) {
                f32x4 x0 = *(const f32x4*)(qp + kc * 32);
                f32x4 x1 = *(const f32x4*)(qp + kc * 32 + 4);
                bf16x8 a;
#pragma unroll
                for (int e = 0; e < 4; ++e) { a[e] = (__bf16)x0[e]; a[e + 4] = (__bf16)x1[e]; }
                qa[u][kc] = a;
            }
        }

        f32x4 oacc[2][8];
#pragma unroll
        for (int u = 0; u < 2; ++u)
#pragma unroll
            for (int i = 0; i < 8; ++i) oacc[u][i] = f32x4{0.f, 0.f, 0.f, 0.f};

        f32x4 kreg[4];
        float vreg[16];

        auto load_chunk = [&](int j0c) {
#pragma unroll
            for (int s = 0; s < 2; ++s) {
                int j = j0c + kj0 + s * 32; if (j > L - 1) j = L - 1;
                const float* p = Kb + (size_t)j * HD + kd8 * 8;
                kreg[s * 2]     = *(const f32x4*)p;
                kreg[s * 2 + 1] = *(const f32x4*)(p + 4);
            }
#pragma unroll
            for (int s = 0; s < 2; ++s) {
                const int gg = vg0 + s * 4;
#pragma unroll
                for (int e = 0; e < 8; ++e) {
                    int j = j0c + gg * 8 + e; if (j > L - 1) j = L - 1;
                    vreg[s * 8 + e] = Vb[(size_t)j * HD + vd];
                }
            }
        };
        auto write_buf = [&](int p) {
            char* wK = smem + p * 32768;
            char* wV = wK + 16384;
#pragma unroll
            for (int s = 0; s < 2; ++s) {
                const int j = kj0 + s * 32;
                bf16x8 kb;
#pragma unroll
                for (int e = 0; e < 4; ++e) { kb[e] = (__bf16)kreg[s*2][e]; kb[e+4] = (__bf16)kreg[s*2+1][e]; }
                *(bf16x8*)(wK + ((j * 256 + kd8 * 16) ^ ((j & 7) << 4))) = kb;
            }
#pragma unroll
            for (int s = 0; s < 2; ++s) {
                bf16x8 vbw;
#pragma unroll
                for (int e = 0; e < 8; ++e) vbw[e] = (__bf16)vreg[s * 8 + e];
                *(bf16x8*)(wV + (vg0 + s * 4) * 2048 + vd * 16) = vbw;
            }
        };

        // prologue: chunk c_lo -> its buf; prefetch c_lo+1
        load_chunk(c_lo << 6);
        write_buf(c_lo & 1);
        if (c_lo + 1 < c_hi) load_chunk((c_lo + 1) << 6);
        asm volatile("s_waitcnt lgkmcnt(0)\n\ts_barrier" ::: "memory");

        for (int c = c_lo; c < c_hi; ++c) {
            const int j0 = c << 6;
            const char* bK = smem + (c & 1) * 32768;
            const char* bV = bK + 16384;

            if (j0 < wave_jmax) {
                unsigned int pk[2][4][2];
                __builtin_amdgcn_s_setprio(1);
#pragma unroll
                for (int jt = 0; jt < 4; ++jt) {
                    const int jl = (jt << 4) + l15;
                    bf16x8 kb[4];
#pragma unroll
                    for (int kc = 0; kc < 4; ++kc) {
                        const int byt = (jl * 256 + (kc * 32 + g8 * 8) * 2) ^ ((jl & 7) << 4);
                        kb[kc] = *(const bf16x8*)(bK + byt);
                    }
#pragma unroll
                    for (int u = 0; u < 2; ++u) {
                        f32x4 sacc = f32x4{0.f, 0.f, 0.f, 0.f};
#pragma unroll
                        for (int kc = 0; kc < 4; ++kc)
                            sacc = __builtin_amdgcn_mfma_f32_16x16x32_bf16(kb[kc], qa[u][kc], sacc, 0, 0, 0);
                        // silu + mask: kv = j0 + 16*jt + 4*g8 + r, q = qrow
                        const int qrow = wr0 + u * 16 + l15;
#pragma unroll
                        for (int r = 0; r < 4; ++r) {
                            const int gj = j0 + (jt << 4) + (g8 << 2) + r;
                            const float e2 = __builtin_amdgcn_exp2f(-(sacc[r] * C2));
                            float p = sacc[r] * C1 * __builtin_amdgcn_rcpf(1.f + e2);
                            const bool valid = (gj < L) && ((gj <= qrow) || (qrow >= cap));
                            sacc[r] = valid ? p : 0.f;
                        }
                        pk[u][jt][0] = cvt_pk_bf16(sacc[0], sacc[1]);
                        pk[u][jt][1] = cvt_pk_bf16(sacc[2], sacc[3]);
                    }
                }
                // ---- in-register P exchange + PV (vb shared across subtiles) ----
#pragma unroll
                for (int kk = 0; kk < 2; ++kk) {
                    PA8 pa[2];
#pragma unroll
                    for (int u = 0; u < 2; ++u)
#pragma unroll
                    for (int hp = 0; hp < 2; ++hp) {
                        const int ad = hp ? addrB : addrA;
#pragma unroll
                        for (int pr = 0; pr < 2; ++pr) {
                            const int ca = __builtin_amdgcn_ds_bpermute(ad, (int)pk[u][2*kk][pr]);
                            const int cb = __builtin_amdgcn_ds_bpermute(ad, (int)pk[u][2*kk+1][pr]);
                            pa[u].u[hp * 2 + pr] = (g8 < 2) ? (unsigned int)ca : (unsigned int)cb;
                        }
                    }
#pragma unroll
                    for (int dt = 0; dt < 8; ++dt) {
                        bf16x8 vb = *(const bf16x8*)(bV + (kk * 4 + g8) * 2048 + ((dt << 4) + l15) * 16);
                        oacc[0][dt] = __builtin_amdgcn_mfma_f32_16x16x32_bf16(pa[0].v, vb, oacc[0][dt], 0, 0, 0);
                        oacc[1][dt] = __builtin_amdgcn_mfma_f32_16x16x32_bf16(pa[1].v, vb, oacc[1][dt], 0, 0, 0);
                    }
                }
                __builtin_amdgcn_s_setprio(0);
            }

            if (c + 1 < c_hi) write_buf((c + 1) & 1);
            if (c + 2 < c_hi) load_chunk((c + 2) << 6);
            // lgkm-only barrier: global prefetch loads stay in flight
            asm volatile("s_waitcnt lgkmcnt(0)\n\ts_barrier" ::: "memory");
        }

        // ---- accumulate O (f32): row wr0+16u+(g8<<2)+r, col dt*16+l15 ----
#pragma unroll
        for (int u = 0; u < 2; ++u)
#pragma unroll
        for (int r = 0; r < 4; ++r) {
            const int gir = wr0 + u * 16 + (g8 << 2) + r;
            if (gir < L) {
                float* op = Out + (size_t)(s0 + gir) * HD + h * 128 + l15;
#pragma unroll
                for (int dt = 0; dt < 8; ++dt)
                    unsafeAtomicAdd(op + (dt << 4), oacc[u][dt][r]);
            }
        }
    }
}

extern "C" void kernel_launch(void* const* d_in, const int* in_sizes, int n_in,
                              void* d_out, int out_size, void* d_ws, size_t ws_size,
                              hipStream_t stream) {
    (void)in_sizes; (void)n_in; (void)ws_size;
    const float* q = (const float*)d_in[0];
    const float* k = (const float*)d_in[1];
    const float* v = (const float*)d_in[2];
    const int* offs = (const int*)d_in[3];
    const int* ntgt = (const int*)d_in[4];
    float* out = (float*)d_out;
    unsigned int* ctr = (unsigned int*)d_ws;
    hipMemsetAsync(out, 0, (size_t)out_size * 4, stream);
    hipMemsetAsync(ctr, 0, 4, stream);
    dim3 grid(512, 1, 1), block(512, 1, 1);
    hipLaunchKernelGGL(hstu_attn_fwd, grid, block, 0, stream, q, k, v, offs, ntgt, out, ctr);
}

// Round 13
// 121.432 us; speedup vs baseline: 1.8143x; 1.8143x over previous
//
#include <hip/hip_runtime.h>

typedef __bf16 bf16x8 __attribute__((ext_vector_type(8)));
typedef float  f32x4  __attribute__((ext_vector_type(4)));

#define HD     512            // H*D
#define NITEMS 2048           // 16 tt-levels x 128 (b,h)
#define C1     8.6316745750310966e-05f  // ALPHA/1024
#define C2     0.12751793f              // ALPHA*log2(e)

static __device__ __forceinline__ unsigned int cvt_pk_bf16(float lo, float hi) {
    unsigned int r;
    asm("v_cvt_pk_bf16_f32 %0, %1, %2" : "=v"(r) : "v"(lo), "v"(hi));
    return r;
}

union PA8 { unsigned int u[4]; bf16x8 v; };

// 4-wave (256-thr) persistent blocks, 4 blocks/CU (33KB LDS, ~110 VGPR) ->
// 4 independent barrier domains per CU (vs 2 for 8-wave blocks: the convoy
// latency, not any pipe, has been the binder since r7).
// Dynamic LPT queue over 64-row tile items (tt-major, biggest first),
// ~1536 valid items for 1024 resident blocks. Plain stores (1 owner/row).
// Per item: KV chunk 32, ping-pong LDS (2 x 16KB), reg-prefetch 2 ahead,
// lgkm-only barriers (global prefetch loads stay in flight across them),
// swapped QK^T -> in-register P exchange via ds_bpermute (r7-verified).
__global__ __launch_bounds__(256)
void hstu_attn_fwd(const float* __restrict__ Q, const float* __restrict__ K,
                   const float* __restrict__ V,
                   const int* __restrict__ offs,
                   const int* __restrict__ ntgt,
                   float* __restrict__ Out,
                   unsigned int* __restrict__ ctr)
{
    __shared__ __align__(16) char smem[32768];
    __shared__ int s_item;

    const int tid = threadIdx.x;
    const int w = tid >> 6, lane = tid & 63, l15 = lane & 15, g8 = lane >> 4;

    // staging decode
    const int kj0 = tid >> 3, kd16 = (tid & 7) * 16;  // K: row kj0, d-base kd16 (16 f32)
    const int vgp = tid >> 7, vd   = tid & 127;       // V: groups vgp*2+s, column vd

    // bpermute addresses for the P exchange (bytes = lane*4)
    const int addrA = ((((g8 & 1) << 5) + l15) << 2);
    const int addrB = addrA + 64;

    for (;;) {
        __syncthreads();
        if (tid == 0) s_item = (int)atomicAdd(ctr, 1u);
        __syncthreads();
        const int it = s_item;
        if (it >= NITEMS) break;

        const int tt = it >> 7;            // 0..15, biggest tiles first
        const int G  = it & 127;
        const int b  = G >> 2, h = G & 3;

        const int s0 = offs[b];
        const int L  = offs[b + 1] - s0;
        const int T  = (L + 63) >> 6;      // 64-row tiles
        const int t  = T - 1 - tt;
        if (t < 0) continue;
        const int cap = L - ntgt[b];

        const float* Kb = K + (size_t)s0 * HD + h * 128;
        const float* Vb = V + (size_t)s0 * HD + h * 128;

        const int r0  = t << 6;
        const int wr0 = r0 + (w << 4);     // wave owns rows wr0..wr0+15

        int wave_jmax;
        if (wr0 >= L)            wave_jmax = 0;
        else if (wr0 + 16 > cap) wave_jmax = L;
        else                     wave_jmax = wr0 + 16;

        const int jmax = (r0 + 64 > cap) ? L : (r0 + 64);
        const int nch  = (jmax + 31) >> 5;

        // ---- Q fragments (B-operand of swapped QK^T) ----
        bf16x8 qa[4];
        {
            int qr = wr0 + l15; if (qr > L - 1) qr = L - 1;
            const float* qp = Q + (size_t)(s0 + qr) * HD + h * 128 + g8 * 8;
#pragma unroll
            for (int kc = 0; kc < 4; ++kc) {
                f32x4 x0 = *(const f32x4*)(qp + kc * 32);
                f32x4 x1 = *(const f32x4*)(qp + kc * 32 + 4);
                bf16x8 a;
#pragma unroll
                for (int e = 0; e < 4; ++e) { a[e] = (__bf16)x0[e]; a[e + 4] = (__bf16)x1[e]; }
                qa[kc] = a;
            }
        }

        f32x4 oacc[8];
#pragma unroll
        for (int i = 0; i < 8; ++i) oacc[i] = f32x4{0.f, 0.f, 0.f, 0.f};

        const int qrow = wr0 + l15;        // this lane's q-row in S^T/P space
        const int gi0  = wr0 + (g8 << 2);  // output C-layout row base

        f32x4 kreg[4];
        float vreg[16];

        auto load_chunk = [&](int j0c) {
            int j = j0c + kj0; if (j > L - 1) j = L - 1;
            const float* p = Kb + (size_t)j * HD + kd16;
#pragma unroll
            for (int q4 = 0; q4 < 4; ++q4) kreg[q4] = *(const f32x4*)(p + q4 * 4);
#pragma unroll
            for (int s = 0; s < 2; ++s) {
                const int gg = vgp * 2 + s;
#pragma unroll
                for (int e = 0; e < 8; ++e) {
                    int jv = j0c + gg * 8 + e; if (jv > L - 1) jv = L - 1;
                    vreg[s * 8 + e] = Vb[(size_t)jv * HD + vd];
                }
            }
        };
        auto write_buf = [&](int p) {
            char* wK = smem + p * 16384;
            char* wV = wK + 8192;
#pragma unroll
            for (int s = 0; s < 2; ++s) {
                bf16x8 kb;
#pragma unroll
                for (int e = 0; e < 4; ++e) { kb[e] = (__bf16)kreg[s*2][e]; kb[e+4] = (__bf16)kreg[s*2+1][e]; }
                *(bf16x8*)(wK + ((kj0 * 256 + kd16 * 2 + s * 16) ^ ((kj0 & 7) << 4))) = kb;
            }
#pragma unroll
            for (int s = 0; s < 2; ++s) {
                bf16x8 vbw;
#pragma unroll
                for (int e = 0; e < 8; ++e) vbw[e] = (__bf16)vreg[s * 8 + e];
                *(bf16x8*)(wV + (vgp * 2 + s) * 2048 + vd * 16) = vbw;
            }
        };

        // prologue: chunk0 -> buf0; prefetch chunk1
        load_chunk(0);
        write_buf(0);
        if (nch > 1) load_chunk(32);
        asm volatile("s_waitcnt lgkmcnt(0)\n\ts_barrier" ::: "memory");

        for (int c = 0; c < nch; ++c) {
            const int j0 = c << 5;
            const char* bK = smem + (c & 1) * 16384;
            const char* bV = bK + 8192;

            if (j0 < wave_jmax) {
                unsigned int pk[2][2];
                __builtin_amdgcn_s_setprio(1);
#pragma unroll
                for (int jt = 0; jt < 2; ++jt) {
                    const int jl = (jt << 4) + l15;
                    f32x4 sacc = f32x4{0.f, 0.f, 0.f, 0.f};
#pragma unroll
                    for (int kc = 0; kc < 4; ++kc) {
                        const int byt = (jl * 256 + (kc * 32 + g8 * 8) * 2) ^ ((jl & 7) << 4);
                        bf16x8 kb = *(const bf16x8*)(bK + byt);
                        sacc = __builtin_amdgcn_mfma_f32_16x16x32_bf16(kb, qa[kc], sacc, 0, 0, 0);
                    }
                    // silu + mask: kv = j0 + 16*jt + 4*g8 + r, q = qrow
#pragma unroll
                    for (int r = 0; r < 4; ++r) {
                        const int gj = j0 + (jt << 4) + (g8 << 2) + r;
                        const float e2 = __builtin_amdgcn_exp2f(-(sacc[r] * C2));
                        float p = sacc[r] * C1 * __builtin_amdgcn_rcpf(1.f + e2);
                        const bool valid = (gj < L) && ((gj <= qrow) || (qrow >= cap));
                        sacc[r] = valid ? p : 0.f;
                    }
                    pk[jt][0] = cvt_pk_bf16(sacc[0], sacc[1]);
                    pk[jt][1] = cvt_pk_bf16(sacc[2], sacc[3]);
                }
                // ---- in-register P exchange + PV (one 32-k group) ----
                PA8 pa;
#pragma unroll
                for (int hp = 0; hp < 2; ++hp) {
                    const int ad = hp ? addrB : addrA;
#pragma unroll
                    for (int pr = 0; pr < 2; ++pr) {
                        const int ca = __builtin_amdgcn_ds_bpermute(ad, (int)pk[0][pr]);
                        const int cb = __builtin_amdgcn_ds_bpermute(ad, (int)pk[1][pr]);
                        pa.u[hp * 2 + pr] = (g8 < 2) ? (unsigned int)ca : (unsigned int)cb;
                    }
                }
#pragma unroll
                for (int dt = 0; dt < 8; ++dt) {
                    bf16x8 vb = *(const bf16x8*)(bV + g8 * 2048 + ((dt << 4) + l15) * 16);
                    oacc[dt] = __builtin_amdgcn_mfma_f32_16x16x32_bf16(pa.v, vb, oacc[dt], 0, 0, 0);
                }
                __builtin_amdgcn_s_setprio(0);
            }

            if (c + 1 < nch) write_buf((c + 1) & 1);
            if (c + 2 < nch) load_chunk((c + 2) << 5);
            // lgkm-only barrier: global prefetch loads stay in flight
            asm volatile("s_waitcnt lgkmcnt(0)\n\ts_barrier" ::: "memory");
        }

        // ---- write O (f32): row gi0+r, col dt*16+l15 ----
#pragma unroll
        for (int r = 0; r < 4; ++r) {
            const int gir = gi0 + r;
            if (gir < L) {
                float* op = Out + (size_t)(s0 + gir) * HD + h * 128 + l15;
#pragma unroll
                for (int dt = 0; dt < 8; ++dt) op[dt << 4] = oacc[dt][r];
            }
        }
    }
}

extern "C" void kernel_launch(void* const* d_in, const int* in_sizes, int n_in,
                              void* d_out, int out_size, void* d_ws, size_t ws_size,
                              hipStream_t stream) {
    (void)in_sizes; (void)n_in; (void)ws_size; (void)out_size;
    const float* q = (const float*)d_in[0];
    const float* k = (const float*)d_in[1];
    const float* v = (const float*)d_in[2];
    const int* offs = (const int*)d_in[3];
    const int* ntgt = (const int*)d_in[4];
    float* out = (float*)d_out;
    unsigned int* ctr = (unsigned int*)d_ws;
    hipMemsetAsync(ctr, 0, 4, stream);
    dim3 grid(1024, 1, 1), block(256, 1, 1);
    hipLaunchKernelGGL(hstu_attn_fwd, grid, block, 0, stream, q, k, v, offs, ntgt, out, ctr);
}

// Round 14
// 118.483 us; speedup vs baseline: 1.8594x; 1.0249x over previous
//
#include <hip/hip_runtime.h>

typedef __bf16 bf16x8 __attribute__((ext_vector_type(8)));
typedef float  f32x4  __attribute__((ext_vector_type(4)));
typedef float  f32x16 __attribute__((ext_vector_type(16)));

#define HD 512            // H*D
#define C1 8.6316745750310966e-05f  // ALPHA/1024
#define C2 0.12751793f              // ALPHA*log2(e)

static __device__ __forceinline__ unsigned int cvt_pk_bf16(float lo, float hi) {
    unsigned int r;
    asm("v_cvt_pk_bf16_f32 %0, %1, %2" : "=v"(r) : "v"(lo), "v"(hi));
    return r;
}

union PA8 { unsigned int u[4]; bf16x8 v; };

// Static big-first dispatch over (q-tile, d-half) items. bx = slot*128 + G;
// tt = slot>>1 (biggest tiles first), dhalf = slot&1; t = T-1-tt; G -> (b,h).
// d-split halves the accumulator (oacc 32 VGPR) and V traffic; the two halves
// write DISJOINT output columns -> plain stores, no atomics, no zeroing.
// 4-wave blocks, 32 q-rows/wave (32x32 MFMA), KV chunk 32, ping-pong LDS
// 2x12KB -> 4 blocks/CU = 4 independent barrier domains (16 waves/CU).
// QK^T runs on full d=128 in both halves (K staged full; +50% global MFMA) —
// the price for fitting 128 VGPR. Swapped QK^T (S^T = mfma32(K,Q)); P goes to
// PV A-frags in-register via v_cvt_pk_bf16_f32 + v_permlane32_swap_b32.
// lgkm-only barriers: global prefetch loads stay in flight across s_barrier.
__global__ __launch_bounds__(256, 4)
void hstu_attn_fwd(const float* __restrict__ Q, const float* __restrict__ K,
                   const float* __restrict__ V,
                   const int* __restrict__ offs,
                   const int* __restrict__ ntgt,
                   float* __restrict__ Out)
{
    __shared__ __align__(16) char smem[24576];   // 2 x (K 8KB + V 4KB)

    const int bx   = blockIdx.x;
    const int G    = bx & 127;
    const int slot = bx >> 7;
    const int tt = slot >> 1, dhalf = slot & 1;
    const int b = G >> 2, h = G & 3;

    const int s0 = offs[b];
    const int L  = offs[b + 1] - s0;
    const int T  = (L + 127) >> 7;      // 128-row tiles
    const int t  = T - 1 - tt;
    if (t < 0) return;
    const int cap = L - ntgt[b];

    const int tid = threadIdx.x;
    const int w = tid >> 6, lane = tid & 63;
    const int l31 = lane & 31, h5 = lane >> 5;

    // staging decode
    const int kj0 = tid >> 3, kd16 = (tid & 7) * 16;  // K: row kj0, d-base (16 f32)
    const int vgp = tid >> 6, vd   = tid & 63;        // V: j-group vgp, col vd (in half)

    const float* Kb = K + (size_t)s0 * HD + h * 128;
    const float* Vb = V + (size_t)s0 * HD + h * 128 + dhalf * 64;

    const int r0   = t << 7;
    const int wr0  = r0 + (w << 5);     // wave owns rows wr0..wr0+31
    const int qrow = wr0 + l31;

    int wave_jmax;
    if (wr0 >= L)            wave_jmax = 0;
    else if (wr0 + 32 > cap) wave_jmax = L;
    else                     wave_jmax = wr0 + 32;

    const int jm  = (r0 + 128 > cap) ? L : (r0 + 128);
    const int nch = (jm + 31) >> 5;

    // ---- Q B-frags (full d): lane reads Q[qrow][ks*16 + h5*8 + e] ----
    bf16x8 qa[8];
    {
        int qr = qrow; if (qr > L - 1) qr = L - 1;
        const float* qp = Q + (size_t)(s0 + qr) * HD + h * 128 + h5 * 8;
#pragma unroll
        for (int ks = 0; ks < 8; ++ks) {
            f32x4 x0 = *(const f32x4*)(qp + ks * 16);
            f32x4 x1 = *(const f32x4*)(qp + ks * 16 + 4);
            bf16x8 a;
#pragma unroll
            for (int e = 0; e < 4; ++e) { a[e] = (__bf16)x0[e]; a[e + 4] = (__bf16)x1[e]; }
            qa[ks] = a;
        }
    }

    f32x16 oacc[2];
#pragma unroll
    for (int d = 0; d < 2; ++d)
#pragma unroll
        for (int r = 0; r < 16; ++r) oacc[d][r] = 0.f;

    f32x4 kreg[4];
    float vreg[8];

    auto load_chunk = [&](int j0c) {
        int j = j0c + kj0; if (j > L - 1) j = L - 1;
        const float* p = Kb + (size_t)j * HD + kd16;
#pragma unroll
        for (int q4 = 0; q4 < 4; ++q4) kreg[q4] = *(const f32x4*)(p + q4 * 4);
#pragma unroll
        for (int e = 0; e < 8; ++e) {
            int jv = j0c + vgp * 8 + e; if (jv > L - 1) jv = L - 1;
            vreg[e] = Vb[(size_t)jv * HD + vd];
        }
    };
    auto write_buf = [&](int p) {
        char* wK = smem + p * 12288;
        char* wV = wK + 8192;
#pragma unroll
        for (int s = 0; s < 2; ++s) {
            bf16x8 kb;
#pragma unroll
            for (int e = 0; e < 4; ++e) { kb[e] = (__bf16)kreg[s*2][e]; kb[e+4] = (__bf16)kreg[s*2+1][e]; }
            *(bf16x8*)(wK + ((kj0 * 256 + kd16 * 2 + s * 16) ^ ((kj0 & 7) << 4))) = kb;
        }
        bf16x8 vbw;
#pragma unroll
        for (int e = 0; e < 8; ++e) vbw[e] = (__bf16)vreg[e];
        *(bf16x8*)(wV + vgp * 1024 + vd * 16) = vbw;
    };

    // prologue: chunk0 -> buf0
    load_chunk(0);
    write_buf(0);
    asm volatile("s_waitcnt lgkmcnt(0)\n\ts_barrier" ::: "memory");

    for (int c = 0; c < nch; ++c) {
        if (c + 1 < nch) load_chunk((c + 1) << 5);   // lands under compute
        const int j0 = c << 5;
        const char* bK = smem + (c & 1) * 12288;
        const char* bV = bK + 8192;

        if (j0 < wave_jmax) {
            // ---- S^T (32 j x 32 q) = mfma32(K, Q) over 8 k-steps (full d) ----
            f32x16 sacc;
#pragma unroll
            for (int r = 0; r < 16; ++r) sacc[r] = 0.f;
            __builtin_amdgcn_s_setprio(1);
#pragma unroll
            for (int ks = 0; ks < 8; ++ks) {
                bf16x8 kb = *(const bf16x8*)(bK +
                    ((l31 * 256 + ks * 32 + h5 * 16) ^ ((l31 & 7) << 4)));
                sacc = __builtin_amdgcn_mfma_f32_32x32x16_bf16(kb, qa[ks], sacc, 0, 0, 0);
            }
            __builtin_amdgcn_s_setprio(0);
            // ---- silu + mask: j = j0 + (r&3)+8(r>>2)+4h5, q = qrow ----
#pragma unroll
            for (int r = 0; r < 16; ++r) {
                const int gj = j0 + (r & 3) + ((r >> 2) << 3) + (h5 << 2);
                const float s = sacc[r];
                const float e2 = __builtin_amdgcn_exp2f(-(s * C2));
                const float p = s * C1 * __builtin_amdgcn_rcpf(1.f + e2);
                const bool valid = (gj < L) && ((gj <= qrow) || (qrow >= cap));
                sacc[r] = valid ? p : 0.f;
            }
            // ---- pack + permlane exchange -> PV A-frags; PV (d-half only) ----
#pragma unroll
            for (int sg = 0; sg < 2; ++sg) {
                unsigned int a  = cvt_pk_bf16(sacc[sg * 8 + 0], sacc[sg * 8 + 1]);
                unsigned int bb = cvt_pk_bf16(sacc[sg * 8 + 2], sacc[sg * 8 + 3]);
                unsigned int cc = cvt_pk_bf16(sacc[sg * 8 + 4], sacc[sg * 8 + 5]);
                unsigned int dd = cvt_pk_bf16(sacc[sg * 8 + 6], sacc[sg * 8 + 7]);
                asm volatile("v_permlane32_swap_b32 %0, %1" : "+v"(a), "+v"(cc));
                asm volatile("v_permlane32_swap_b32 %0, %1" : "+v"(bb), "+v"(dd));
                PA8 pa;
                pa.u[0] = a; pa.u[1] = bb; pa.u[2] = cc; pa.u[3] = dd;
                __builtin_amdgcn_s_setprio(1);
#pragma unroll
                for (int dt = 0; dt < 2; ++dt) {
                    bf16x8 vb = *(const bf16x8*)(bV + (sg * 2 + h5) * 1024 +
                                                 (dt * 32 + l31) * 16);
                    oacc[dt] = __builtin_amdgcn_mfma_f32_32x32x16_bf16(pa.v, vb, oacc[dt], 0, 0, 0);
                }
                __builtin_amdgcn_s_setprio(0);
            }
        }

        if (c + 1 < nch) write_buf((c + 1) & 1);
        // lgkm-only barrier: global prefetch loads stay in flight
        asm volatile("s_waitcnt lgkmcnt(0)\n\ts_barrier" ::: "memory");
    }

    // ---- write O (f32): row = wr0+(r&3)+8(r>>2)+4h5, col = dhalf*64+dt*32+l31 ----
#pragma unroll
    for (int r = 0; r < 16; ++r) {
        const int gir = wr0 + (r & 3) + ((r >> 2) << 3) + (h5 << 2);
        if (gir < L) {
            float* op = Out + (size_t)(s0 + gir) * HD + h * 128 + dhalf * 64 + l31;
            op[0]  = oacc[0][r];
            op[32] = oacc[1][r];
        }
    }
}

extern "C" void kernel_launch(void* const* d_in, const int* in_sizes, int n_in,
                              void* d_out, int out_size, void* d_ws, size_t ws_size,
                              hipStream_t stream) {
    (void)in_sizes; (void)n_in; (void)d_ws; (void)ws_size; (void)out_size;
    const float* q = (const float*)d_in[0];
    const float* k = (const float*)d_in[1];
    const float* v = (const float*)d_in[2];
    const int* offs = (const int*)d_in[3];
    const int* ntgt = (const int*)d_in[4];
    float* out = (float*)d_out;
    dim3 grid(2048, 1, 1), block(256, 1, 1);
    hipLaunchKernelGGL(hstu_attn_fwd, grid, block, 0, stream, q, k, v, offs, ntgt, out);
}

// Round 15
// 110.568 us; speedup vs baseline: 1.9925x; 1.0716x over previous
//
#include <hip/hip_runtime.h>

typedef __bf16 bf16x8 __attribute__((ext_vector_type(8)));
typedef float  f32x4  __attribute__((ext_vector_type(4)));
typedef float  f32x16 __attribute__((ext_vector_type(16)));

#define HD 512            // H*D
#define C1 8.6316745750310966e-05f  // ALPHA/1024
#define C2 0.12751793f              // ALPHA*log2(e)

static __device__ __forceinline__ unsigned int cvt_pk_bf16(float lo, float hi) {
    unsigned int r;
    asm("v_cvt_pk_bf16_f32 %0, %1, %2" : "=v"(r) : "v"(lo), "v"(hi));
    return r;
}

union PA8 { unsigned int u[4]; bf16x8 v; };

// Static big-first dispatch over (q-tile, d-half) items. bx = slot*128 + G;
// tt = slot>>1 (biggest tiles first), dhalf = slot&1; t = T-1-tt; G -> (b,h).
// d-split halves the accumulator (oacc 32 VGPR) and V traffic; the two halves
// write DISJOINT output columns -> plain stores, no atomics, no zeroing.
// 4-wave blocks, 32 q-rows/wave (32x32 MFMA), KV chunk 32, ping-pong LDS
// 2x12KB -> 4 blocks/CU = 4 independent barrier domains (16 waves/CU).
// QK^T runs on full d=128 in both halves (K staged full; +50% global MFMA).
// Swapped QK^T (S^T = mfma32(K,Q)); P -> PV A-frags in-register via
// v_cvt_pk_bf16_f32 + v_permlane32_swap_b32. lgkm-only barriers.
// PLAIN __launch_bounds__(256): the ",4" variant forced VGPR=64 and spilled
// ~50 live regs (r10: 294us, r14: 118us). Target ~110-126 VGPR naturally.
__global__ __launch_bounds__(256)
void hstu_attn_fwd(const float* __restrict__ Q, const float* __restrict__ K,
                   const float* __restrict__ V,
                   const int* __restrict__ offs,
                   const int* __restrict__ ntgt,
                   float* __restrict__ Out)
{
    __shared__ __align__(16) char smem[24576];   // 2 x (K 8KB + V 4KB)

    const int bx   = blockIdx.x;
    const int G    = bx & 127;
    const int slot = bx >> 7;
    const int tt = slot >> 1, dhalf = slot & 1;
    const int b = G >> 2, h = G & 3;

    const int s0 = offs[b];
    const int L  = offs[b + 1] - s0;
    const int T  = (L + 127) >> 7;      // 128-row tiles
    const int t  = T - 1 - tt;
    if (t < 0) return;
    const int cap = L - ntgt[b];

    const int tid = threadIdx.x;
    const int w = tid >> 6, lane = tid & 63;
    const int l31 = lane & 31, h5 = lane >> 5;

    // staging decode
    const int kj0 = tid >> 3, kd16 = (tid & 7) * 16;  // K: row kj0, d-base (16 f32)
    const int vgp = tid >> 6, vd   = tid & 63;        // V: j-group vgp, col vd (in half)

    const float* Kb = K + (size_t)s0 * HD + h * 128;
    const float* Vb = V + (size_t)s0 * HD + h * 128 + dhalf * 64;

    const int r0   = t << 7;
    const int wr0  = r0 + (w << 5);     // wave owns rows wr0..wr0+31
    const int qrow = wr0 + l31;

    int wave_jmax;
    if (wr0 >= L)            wave_jmax = 0;
    else if (wr0 + 32 > cap) wave_jmax = L;
    else                     wave_jmax = wr0 + 32;

    const int jm  = (r0 + 128 > cap) ? L : (r0 + 128);
    const int nch = (jm + 31) >> 5;

    // ---- Q B-frags (full d): lane reads Q[qrow][ks*16 + h5*8 + e] ----
    bf16x8 qa[8];
    {
        int qr = qrow; if (qr > L - 1) qr = L - 1;
        const float* qp = Q + (size_t)(s0 + qr) * HD + h * 128 + h5 * 8;
#pragma unroll
        for (int ks = 0; ks < 8; ++ks) {
            f32x4 x0 = *(const f32x4*)(qp + ks * 16);
            f32x4 x1 = *(const f32x4*)(qp + ks * 16 + 4);
            bf16x8 a;
#pragma unroll
            for (int e = 0; e < 4; ++e) { a[e] = (__bf16)x0[e]; a[e + 4] = (__bf16)x1[e]; }
            qa[ks] = a;
        }
    }

    f32x16 oacc[2];
#pragma unroll
    for (int d = 0; d < 2; ++d)
#pragma unroll
        for (int r = 0; r < 16; ++r) oacc[d][r] = 0.f;

    f32x4 kreg[4];
    float vreg[8];

    auto load_chunk = [&](int j0c) {
        int j = j0c + kj0; if (j > L - 1) j = L - 1;
        const float* p = Kb + (size_t)j * HD + kd16;
#pragma unroll
        for (int q4 = 0; q4 < 4; ++q4) kreg[q4] = *(const f32x4*)(p + q4 * 4);
#pragma unroll
        for (int e = 0; e < 8; ++e) {
            int jv = j0c + vgp * 8 + e; if (jv > L - 1) jv = L - 1;
            vreg[e] = Vb[(size_t)jv * HD + vd];
        }
    };
    auto write_buf = [&](int p) {
        char* wK = smem + p * 12288;
        char* wV = wK + 8192;
#pragma unroll
        for (int s = 0; s < 2; ++s) {
            bf16x8 kb;
#pragma unroll
            for (int e = 0; e < 4; ++e) { kb[e] = (__bf16)kreg[s*2][e]; kb[e+4] = (__bf16)kreg[s*2+1][e]; }
            *(bf16x8*)(wK + ((kj0 * 256 + kd16 * 2 + s * 16) ^ ((kj0 & 7) << 4))) = kb;
        }
        bf16x8 vbw;
#pragma unroll
        for (int e = 0; e < 8; ++e) vbw[e] = (__bf16)vreg[e];
        *(bf16x8*)(wV + vgp * 1024 + vd * 16) = vbw;
    };

    // prologue: chunk0 -> buf0
    load_chunk(0);
    write_buf(0);
    asm volatile("s_waitcnt lgkmcnt(0)\n\ts_barrier" ::: "memory");

    for (int c = 0; c < nch; ++c) {
        if (c + 1 < nch) load_chunk((c + 1) << 5);   // lands under compute
        const int j0 = c << 5;
        const char* bK = smem + (c & 1) * 12288;
        const char* bV = bK + 8192;

        if (j0 < wave_jmax) {
            // ---- S^T (32 j x 32 q) = mfma32(K, Q) over 8 k-steps (full d) ----
            f32x16 sacc;
#pragma unroll
            for (int r = 0; r < 16; ++r) sacc[r] = 0.f;
            __builtin_amdgcn_s_setprio(1);
#pragma unroll
            for (int ks = 0; ks < 8; ++ks) {
                bf16x8 kb = *(const bf16x8*)(bK +
                    ((l31 * 256 + ks * 32 + h5 * 16) ^ ((l31 & 7) << 4)));
                sacc = __builtin_amdgcn_mfma_f32_32x32x16_bf16(kb, qa[ks], sacc, 0, 0, 0);
            }
            __builtin_amdgcn_s_setprio(0);
            // ---- silu + mask: j = j0 + (r&3)+8(r>>2)+4h5, q = qrow ----
#pragma unroll
            for (int r = 0; r < 16; ++r) {
                const int gj = j0 + (r & 3) + ((r >> 2) << 3) + (h5 << 2);
                const float s = sacc[r];
                const float e2 = __builtin_amdgcn_exp2f(-(s * C2));
                const float p = s * C1 * __builtin_amdgcn_rcpf(1.f + e2);
                const bool valid = (gj < L) && ((gj <= qrow) || (qrow >= cap));
                sacc[r] = valid ? p : 0.f;
            }
            // ---- pack + permlane exchange -> PV A-frags; PV (d-half only) ----
#pragma unroll
            for (int sg = 0; sg < 2; ++sg) {
                unsigned int a  = cvt_pk_bf16(sacc[sg * 8 + 0], sacc[sg * 8 + 1]);
                unsigned int bb = cvt_pk_bf16(sacc[sg * 8 + 2], sacc[sg * 8 + 3]);
                unsigned int cc = cvt_pk_bf16(sacc[sg * 8 + 4], sacc[sg * 8 + 5]);
                unsigned int dd = cvt_pk_bf16(sacc[sg * 8 + 6], sacc[sg * 8 + 7]);
                asm volatile("v_permlane32_swap_b32 %0, %1" : "+v"(a), "+v"(cc));
                asm volatile("v_permlane32_swap_b32 %0, %1" : "+v"(bb), "+v"(dd));
                PA8 pa;
                pa.u[0] = a; pa.u[1] = bb; pa.u[2] = cc; pa.u[3] = dd;
                __builtin_amdgcn_s_setprio(1);
#pragma unroll
                for (int dt = 0; dt < 2; ++dt) {
                    bf16x8 vb = *(const bf16x8*)(bV + (sg * 2 + h5) * 1024 +
                                                 (dt * 32 + l31) * 16);
                    oacc[dt] = __builtin_amdgcn_mfma_f32_32x32x16_bf16(pa.v, vb, oacc[dt], 0, 0, 0);
                }
                __builtin_amdgcn_s_setprio(0);
            }
        }

        if (c + 1 < nch) write_buf((c + 1) & 1);
        // lgkm-only barrier: global prefetch loads stay in flight
        asm volatile("s_waitcnt lgkmcnt(0)\n\ts_barrier" ::: "memory");
    }

    // ---- write O (f32): row = wr0+(r&3)+8(r>>2)+4h5, col = dhalf*64+dt*32+l31 ----
#pragma unroll
    for (int r = 0; r < 16; ++r) {
        const int gir = wr0 + (r & 3) + ((r >> 2) << 3) + (h5 << 2);
        if (gir < L) {
            float* op = Out + (size_t)(s0 + gir) * HD + h * 128 + dhalf * 64 + l31;
            op[0]  = oacc[0][r];
            op[32] = oacc[1][r];
        }
    }
}

extern "C" void kernel_launch(void* const* d_in, const int* in_sizes, int n_in,
                              void* d_out, int out_size, void* d_ws, size_t ws_size,
                              hipStream_t stream) {
    (void)in_sizes; (void)n_in; (void)d_ws; (void)ws_size; (void)out_size;
    const float* q = (const float*)d_in[0];
    const float* k = (const float*)d_in[1];
    const float* v = (const float*)d_in[2];
    const int* offs = (const int*)d_in[3];
    const int* ntgt = (const int*)d_in[4];
    float* out = (float*)d_out;
    dim3 grid(2048, 1, 1), block(256, 1, 1);
    hipLaunchKernelGGL(hstu_attn_fwd, grid, block, 0, stream, q, k, v, offs, ntgt, out);
}